// Round 13
// baseline (163.805 us; speedup 1.0000x reference)
//
#include <hip/hip_runtime.h>
#include <math.h>

#define C_IN 16
#define NTH 256
#define BKT_SHIFT 8            // 256 nodes per bucket
#define NBK_MAX 1024

typedef __attribute__((ext_vector_type(8))) short bf16x8;
typedef __attribute__((ext_vector_type(8))) unsigned short u16x8;
typedef __attribute__((ext_vector_type(4))) unsigned short u16x4;
typedef __attribute__((ext_vector_type(4))) float f32x4;

__device__ __forceinline__ unsigned short f2bf(float f) {
    unsigned int u = __float_as_uint(f);
    unsigned int r = (u + 0x7FFFu + ((u >> 16) & 1u)) >> 16;   // RNE
    return (unsigned short)r;
}
__device__ __forceinline__ float bf2f(unsigned short u) {
    return __uint_as_float(((unsigned int)u) << 16);
}

// ---------------- bucket histogram (128 fat blocks, LDS hist, few global atomics) ------
__global__ __launch_bounds__(NTH) void bkt_hist_kernel(const int* __restrict__ dst, int E,
                                                       int nbk, int* __restrict__ bcnt) {
    __shared__ int h[NBK_MAX];
    for (int i = threadIdx.x; i < nbk; i += NTH) h[i] = 0;
    __syncthreads();
    for (int e = blockIdx.x * NTH + threadIdx.x; e < E; e += gridDim.x * NTH)
        atomicAdd(&h[dst[e] >> BKT_SHIFT], 1);
    __syncthreads();
    for (int i = threadIdx.x; i < nbk; i += NTH)
        if (h[i]) atomicAdd(&bcnt[i], h[i]);
}

// ---------------- bucket scan (1 block); also writes row[n] = E ------------------------
__global__ __launch_bounds__(NTH) void bkt_scan_kernel(const int* __restrict__ bcnt, int nbk,
                                                       int* __restrict__ bbase,
                                                       int* __restrict__ bcur,
                                                       int* __restrict__ row, int n) {
    __shared__ int s[NBK_MAX + 1];
    for (int i = threadIdx.x; i < nbk; i += NTH) s[i] = bcnt[i];
    __syncthreads();
    if (threadIdx.x == 0) {
        int acc = 0;
        for (int i = 0; i < nbk; ++i) { int v = s[i]; s[i] = acc; acc += v; }
        s[nbk] = acc;
        row[n] = acc;
    }
    __syncthreads();
    for (int i = threadIdx.x; i <= nbk; i += NTH) bbase[i] = s[i];
    for (int i = threadIdx.x; i < nbk; i += NTH) bcur[i] = s[i];
}

// ---------------- bucket scatter: append (src,dst) into per-bucket regions -------------
__global__ __launch_bounds__(NTH) void bkt_scatter_kernel(const int* __restrict__ src,
                                                          const int* __restrict__ dst, int E,
                                                          int nbk, int* __restrict__ bcur,
                                                          int2* __restrict__ pairs) {
    __shared__ int h[NBK_MAX];
    __shared__ int base[NBK_MAX];
    const int chunk = (E + gridDim.x - 1) / gridDim.x;
    const int e0 = blockIdx.x * chunk;
    const int e1 = min(e0 + chunk, E);

    for (int i = threadIdx.x; i < nbk; i += NTH) h[i] = 0;
    __syncthreads();
    for (int e = e0 + threadIdx.x; e < e1; e += NTH)
        atomicAdd(&h[dst[e] >> BKT_SHIFT], 1);
    __syncthreads();
    for (int i = threadIdx.x; i < nbk; i += NTH) {
        int c = h[i];
        base[i] = c ? atomicAdd(&bcur[i], c) : 0;
    }
    __syncthreads();
    for (int i = threadIdx.x; i < nbk; i += NTH) h[i] = 0;
    __syncthreads();
    for (int e = e0 + threadIdx.x; e < e1; e += NTH) {
        int d = dst[e];
        int b = d >> BKT_SHIFT;
        int p = base[b] + atomicAdd(&h[b], 1);
        pairs[p] = make_int2(src[e], d);
    }
}

// ---------------- fused per-bucket build; xs1 written as bf16 (x * dinv) ---------------
__global__ __launch_bounds__(NTH) void build_kernel(const int2* __restrict__ pairs,
                                                    const int* __restrict__ bbase,
                                                    int n,
                                                    int* __restrict__ row,
                                                    int* __restrict__ csr,
                                                    float* __restrict__ dinv,
                                                    float* __restrict__ invdeg,
                                                    const float* __restrict__ x,
                                                    unsigned short* __restrict__ xs) {
    __shared__ int hc[256];
    __shared__ int hcur[256];
    const int t = threadIdx.x;
    const int b = blockIdx.x;
    const int p0 = bbase[b], p1 = bbase[b + 1];

    hc[t] = 0;
    __syncthreads();
    for (int p = p0 + t; p < p1; p += NTH)
        atomicAdd(&hc[pairs[p].y & 255], 1);
    __syncthreads();

    const int myc = hc[t];
    for (int off = 1; off < 256; off <<= 1) {
        int v = (t >= off) ? hc[t - off] : 0;
        __syncthreads();
        hc[t] += v;
        __syncthreads();
    }
    const int excl = hc[t] - myc;
    const int r = p0 + excl;
    hcur[t] = r;

    const int gi = b * 256 + t;
    if (gi < n) {
        row[gi] = r;
        float d = (float)myc + 1.0f;
        float di = rsqrtf(d);
        dinv[gi] = di;
        invdeg[gi] = 1.0f / d;
        const float4* xv = reinterpret_cast<const float4*>(x + (size_t)gi * C_IN);
        u16x8* xsv = reinterpret_cast<u16x8*>(xs + (size_t)gi * C_IN);
        #pragma unroll
        for (int h8 = 0; h8 < 2; ++h8) {
            float4 v0 = xv[h8 * 2], v1 = xv[h8 * 2 + 1];
            u16x8 w;
            w[0] = f2bf(v0.x * di); w[1] = f2bf(v0.y * di);
            w[2] = f2bf(v0.z * di); w[3] = f2bf(v0.w * di);
            w[4] = f2bf(v1.x * di); w[5] = f2bf(v1.y * di);
            w[6] = f2bf(v1.z * di); w[7] = f2bf(v1.w * di);
            xsv[h8] = w;
        }
    }
    __syncthreads();

    for (int p = p0 + t; p < p1; p += NTH) {
        int2 pr = pairs[p];
        int pos = atomicAdd(&hcur[pr.y & 255], 1);
        csr[pos] = pr.x;
    }
}

// ---------------- bf16-source CSR gather ----------------------------------------------
// out[i] = dinv[i]*sum_bf16(xs[src]) + invdeg[i]*self[i] (+bias, relu if FINAL)
// SELFBF: self operand stored bf16. FINAL: output bf16 (RNE identical to MLP's input cvt).
template<int C, bool FINAL, bool SELFBF>
__global__ __launch_bounds__(NTH) void gather_bf_kernel(const int* __restrict__ row,
                                                        const int* __restrict__ csr,
                                                        const unsigned short* __restrict__ xs,
                                                        const void* __restrict__ selfp,
                                                        const float* __restrict__ dinv,
                                                        const float* __restrict__ invdeg,
                                                        const float* __restrict__ bias,
                                                        void* __restrict__ outp, int n) {
    constexpr int G = C / 8;                    // threads per node
    int i = blockIdx.x * (NTH / G) + threadIdx.x / G;
    int q = threadIdx.x % G;
    if (i >= n) return;
    int r0 = row[i], r1 = row[i + 1];

    float a[8];
    #pragma unroll
    for (int c = 0; c < 8; ++c) a[c] = 0.f;

    int e = r0;
    for (; e + 7 < r1; e += 8) {
        int s[8];
        #pragma unroll
        for (int j = 0; j < 8; ++j) s[j] = csr[e + j];
        u16x8 v[8];
        #pragma unroll
        for (int j = 0; j < 8; ++j)
            v[j] = *reinterpret_cast<const u16x8*>(xs + (size_t)s[j] * C + q * 8);
        #pragma unroll
        for (int j = 0; j < 8; ++j) {
            #pragma unroll
            for (int c = 0; c < 8; ++c) a[c] += bf2f(v[j][c]);
        }
    }
    for (; e < r1; ++e) {
        int s0 = csr[e];
        u16x8 v = *reinterpret_cast<const u16x8*>(xs + (size_t)s0 * C + q * 8);
        #pragma unroll
        for (int c = 0; c < 8; ++c) a[c] += bf2f(v[c]);
    }

    float di = dinv[i], idg = invdeg[i];
    float sv[8];
    if (SELFBF) {
        u16x8 s8 = *reinterpret_cast<const u16x8*>((const unsigned short*)selfp + (size_t)i * C + q * 8);
        #pragma unroll
        for (int c = 0; c < 8; ++c) sv[c] = bf2f(s8[c]);
    } else {
        const float* selff = (const float*)selfp;
        const float4 s0 = *reinterpret_cast<const float4*>(selff + (size_t)i * C + q * 8);
        const float4 s1 = *reinterpret_cast<const float4*>(selff + (size_t)i * C + q * 8 + 4);
        sv[0] = s0.x; sv[1] = s0.y; sv[2] = s0.z; sv[3] = s0.w;
        sv[4] = s1.x; sv[5] = s1.y; sv[6] = s1.z; sv[7] = s1.w;
    }
    float o[8];
    #pragma unroll
    for (int c = 0; c < 8; ++c) o[c] = fmaf(a[c], di, sv[c] * idg);

    if (FINAL) {
        const float4 b0 = *reinterpret_cast<const float4*>(bias + q * 8);
        const float4 b1 = *reinterpret_cast<const float4*>(bias + q * 8 + 4);
        o[0] = fmaxf(o[0] + b0.x, 0.f); o[1] = fmaxf(o[1] + b0.y, 0.f);
        o[2] = fmaxf(o[2] + b0.z, 0.f); o[3] = fmaxf(o[3] + b0.w, 0.f);
        o[4] = fmaxf(o[4] + b1.x, 0.f); o[5] = fmaxf(o[5] + b1.y, 0.f);
        o[6] = fmaxf(o[6] + b1.z, 0.f); o[7] = fmaxf(o[7] + b1.w, 0.f);
        u16x8 ob;
        #pragma unroll
        for (int c = 0; c < 8; ++c) ob[c] = f2bf(o[c]);
        *reinterpret_cast<u16x8*>((unsigned short*)outp + (size_t)i * C + q * 8) = ob;
    } else {
        float* outf = (float*)outp;
        float4 w0, w1;
        w0.x = o[0]; w0.y = o[1]; w0.z = o[2]; w0.w = o[3];
        w1.x = o[4]; w1.y = o[5]; w1.z = o[6]; w1.w = o[7];
        *reinterpret_cast<float4*>(outf + (size_t)i * C + q * 8) = w0;
        *reinterpret_cast<float4*>(outf + (size_t)i * C + q * 8 + 4) = w1;
    }
}

// ---------------- transform1: ga1(16) -> relu(·W1+b1)(32) -> h1 fp32 + xs2 bf16*dinv ---
__global__ __launch_bounds__(NTH) void transform1_kernel(const float* __restrict__ g,
                                                         const float* __restrict__ W,
                                                         const float* __restrict__ b,
                                                         const float* __restrict__ dinv,
                                                         float* __restrict__ h,
                                                         unsigned short* __restrict__ hsc,
                                                         int n) {
    __shared__ float Ws[16 * 32];
    __shared__ float bs[32];
    for (int idx = threadIdx.x; idx < 16 * 32; idx += NTH) Ws[idx] = W[idx];
    if (threadIdx.x < 32) bs[threadIdx.x] = b[threadIdx.x];
    __syncthreads();

    int i = blockIdx.x * NTH + threadIdx.x;
    if (i >= n) return;

    float xr[16];
    const float4* xv = reinterpret_cast<const float4*>(g + (size_t)i * 16);
    #pragma unroll
    for (int k4 = 0; k4 < 4; ++k4) {
        float4 v = xv[k4];
        xr[k4*4+0] = v.x; xr[k4*4+1] = v.y; xr[k4*4+2] = v.z; xr[k4*4+3] = v.w;
    }

    float di = dinv[i];
    float4* hv = reinterpret_cast<float4*>(h + (size_t)i * 32);
    u16x4* hscv = reinterpret_cast<u16x4*>(hsc + (size_t)i * 32);

    #pragma unroll 1
    for (int c4 = 0; c4 < 8; ++c4) {
        float a0 = 0.f, a1 = 0.f, a2 = 0.f, a3 = 0.f;
        #pragma unroll
        for (int k = 0; k < 16; ++k) {
            const float4 w = *reinterpret_cast<const float4*>(&Ws[k * 32 + c4 * 4]);
            float xk = xr[k];
            a0 = fmaf(xk, w.x, a0);
            a1 = fmaf(xk, w.y, a1);
            a2 = fmaf(xk, w.z, a2);
            a3 = fmaf(xk, w.w, a3);
        }
        const float4 bv = *reinterpret_cast<const float4*>(&bs[c4 * 4]);
        a0 = fmaxf(a0 + bv.x, 0.f);
        a1 = fmaxf(a1 + bv.y, 0.f);
        a2 = fmaxf(a2 + bv.z, 0.f);
        a3 = fmaxf(a3 + bv.w, 0.f);
        float4 o; o.x = a0; o.y = a1; o.z = a2; o.w = a3;
        hv[c4] = o;
        u16x4 s;
        s[0] = f2bf(a0 * di); s[1] = f2bf(a1 * di);
        s[2] = f2bf(a2 * di); s[3] = f2bf(a3 * di);
        hscv[c4] = s;
    }
}

// ---------------- fused transform2+3, spill-free (R12 fix) ----------------------------
// hh[64] array eliminated by loop interchange: for each hidden unit k2, compute
// hk = relu(b2[k2] + xr . W2T[k2]) then rank-1 update o[0..31] += hk * W3[k2][.].
// Live set: xr[32] + o[32] + hk ~= 70 VGPR -> no scratch (was: hh[64]+xr[32] spilled,
// WRITE_SIZE 22.4MB vs 9.6 logical, 49us cold). W2 staged transposed for contiguous reads.
// Outputs: t3 bf16 (self for gather3), ts3 bf16 (= t3 * dinv, gather3 source).
__global__ __launch_bounds__(NTH) void transform23_kernel(const float* __restrict__ g,
                                                          const float* __restrict__ W2,
                                                          const float* __restrict__ b2,
                                                          const float* __restrict__ W3,
                                                          const float* __restrict__ dinv,
                                                          unsigned short* __restrict__ t3,
                                                          unsigned short* __restrict__ ts3,
                                                          int n) {
    __shared__ float Ws2T[64 * 32];   // [k2][j] = W2[j][k2]
    __shared__ float Ws3[64 * 32];    // [k2][c]
    __shared__ float bs2[64];
    for (int idx = threadIdx.x; idx < 2048; idx += NTH) {
        int k2 = idx >> 5, j = idx & 31;
        Ws2T[idx] = W2[j * 64 + k2];
        Ws3[idx] = W3[idx];
    }
    if (threadIdx.x < 64) bs2[threadIdx.x] = b2[threadIdx.x];
    __syncthreads();

    int i = blockIdx.x * NTH + threadIdx.x;
    if (i >= n) return;

    float xr[32];
    const float4* xv = reinterpret_cast<const float4*>(g + (size_t)i * 32);
    #pragma unroll
    for (int k4 = 0; k4 < 8; ++k4) {
        float4 v = xv[k4];
        xr[k4*4+0] = v.x; xr[k4*4+1] = v.y; xr[k4*4+2] = v.z; xr[k4*4+3] = v.w;
    }

    float o[32];
    #pragma unroll
    for (int c = 0; c < 32; ++c) o[c] = 0.f;

    #pragma unroll 2
    for (int k2 = 0; k2 < 64; ++k2) {
        float hk = bs2[k2];
        const float4* wrow = reinterpret_cast<const float4*>(&Ws2T[k2 * 32]);
        #pragma unroll
        for (int j4 = 0; j4 < 8; ++j4) {
            const float4 w = wrow[j4];
            hk = fmaf(xr[j4*4+0], w.x, hk);
            hk = fmaf(xr[j4*4+1], w.y, hk);
            hk = fmaf(xr[j4*4+2], w.z, hk);
            hk = fmaf(xr[j4*4+3], w.w, hk);
        }
        hk = fmaxf(hk, 0.f);
        const float4* w3row = reinterpret_cast<const float4*>(&Ws3[k2 * 32]);
        #pragma unroll
        for (int c4 = 0; c4 < 8; ++c4) {
            const float4 w = w3row[c4];
            o[c4*4+0] = fmaf(hk, w.x, o[c4*4+0]);
            o[c4*4+1] = fmaf(hk, w.y, o[c4*4+1]);
            o[c4*4+2] = fmaf(hk, w.z, o[c4*4+2]);
            o[c4*4+3] = fmaf(hk, w.w, o[c4*4+3]);
        }
    }

    float dv = dinv[i];
    u16x8* t3v = reinterpret_cast<u16x8*>(t3 + (size_t)i * 32);
    u16x8* ts3v = reinterpret_cast<u16x8*>(ts3 + (size_t)i * 32);
    #pragma unroll
    for (int c8 = 0; c8 < 4; ++c8) {
        u16x8 a, s;
        #pragma unroll
        for (int c = 0; c < 8; ++c) {
            float v = o[c8*8+c];
            a[c] = f2bf(v);
            s[c] = f2bf(v * dv);
        }
        t3v[c8] = a;
        ts3v[c8] = s;
    }
}

// ---------------- MLP head via MFMA; h3 already bf16 (layouts m89-verified) ------------
__global__ __launch_bounds__(NTH, 2) void mlp_mfma_kernel(const unsigned short* __restrict__ h3,
                                                          const float* __restrict__ Wf1,
                                                          const float* __restrict__ bf1,
                                                          const float* __restrict__ Wf2,
                                                          float* __restrict__ part, int n) {
    __shared__ unsigned short lds_w[32 * 512];   // 32 KB, [jt][lane][e]
    __shared__ float b1s[512];
    __shared__ float w2s[512];
    const int tid = threadIdx.x;
    const int jh = blockIdx.y;                   // j-half

    for (int idx = tid; idx < 32 * 512; idx += NTH) {
        int k = idx >> 9, jj = idx & 511;        // coalesced over jj
        float wv = Wf1[k * 1024 + jh * 512 + jj];
        int l = ((k >> 3) << 4) | (jj & 15);
        int jt = jj >> 4;
        lds_w[(jt * 64 + l) * 8 + (k & 7)] = f2bf(wv);
    }
    for (int idx = tid; idx < 512; idx += NTH) {
        b1s[idx] = bf1[jh * 512 + idx];
        w2s[idx] = Wf2[jh * 512 + idx];
    }
    __syncthreads();

    const int wid = tid >> 6, lane = tid & 63;
    const int r16 = lane & 15;
    const int kb = (lane >> 4) * 8;
    float* slice = part + (size_t)jh * n;

    #pragma unroll 1
    for (int tt = 0; tt < 8; ++tt) {
        const int i0 = blockIdx.x * 512 + (wid * 8 + tt) * 16;
        const int ia = i0 + r16;

        bf16x8 af;
        if (ia < n) {
            af = *reinterpret_cast<const bf16x8*>(h3 + (size_t)ia * 32 + kb);
        } else {
            #pragma unroll
            for (int e = 0; e < 8; ++e) af[e] = 0;
        }

        float p0 = 0.f, p1 = 0.f, p2 = 0.f, p3 = 0.f;
        #pragma unroll 4
        for (int jt = 0; jt < 32; ++jt) {
            const bf16x8 bf = *reinterpret_cast<const bf16x8*>(&lds_w[(jt * 64 + lane) * 8]);
            const float bj = b1s[jt * 16 + r16];
            f32x4 cc; cc[0] = bj; cc[1] = bj; cc[2] = bj; cc[3] = bj;
            f32x4 acc = __builtin_amdgcn_mfma_f32_16x16x32_bf16(af, bf, cc, 0, 0, 0);
            const float gj = w2s[jt * 16 + r16];
            p0 = fmaf(fmaxf(acc[0], 0.f), gj, p0);
            p1 = fmaf(fmaxf(acc[1], 0.f), gj, p1);
            p2 = fmaf(fmaxf(acc[2], 0.f), gj, p2);
            p3 = fmaf(fmaxf(acc[3], 0.f), gj, p3);
        }
        #pragma unroll
        for (int m = 1; m < 16; m <<= 1) {
            p0 += __shfl_xor(p0, m, 64);
            p1 += __shfl_xor(p1, m, 64);
            p2 += __shfl_xor(p2, m, 64);
            p3 += __shfl_xor(p3, m, 64);
        }
        if (r16 == 0) {
            const int rbase = i0 + (lane >> 4) * 4;
            if (rbase + 0 < n) slice[rbase + 0] = p0;
            if (rbase + 1 < n) slice[rbase + 1] = p1;
            if (rbase + 2 < n) slice[rbase + 2] = p2;
            if (rbase + 3 < n) slice[rbase + 3] = p3;
        }
    }
}

__global__ __launch_bounds__(NTH) void sigmoid_kernel(const float* __restrict__ part,
                                                      const float* __restrict__ bf2,
                                                      float* __restrict__ out, int n) {
    int i = blockIdx.x * NTH + threadIdx.x;
    if (i < n) {
        float z = bf2[0] + part[i] + part[(size_t)n + i];
        out[i] = 1.0f / (1.0f + expf(-z));
    }
}

extern "C" void kernel_launch(void* const* d_in, const int* in_sizes, int n_in,
                              void* d_out, int out_size, void* d_ws, size_t ws_size,
                              hipStream_t stream) {
    const float* x    = (const float*)d_in[0];
    const int*   ei   = (const int*)d_in[1];
    const float* W1   = (const float*)d_in[2];
    const float* b1   = (const float*)d_in[3];
    const float* W2   = (const float*)d_in[4];
    const float* b2   = (const float*)d_in[5];
    const float* W3   = (const float*)d_in[6];
    const float* b3   = (const float*)d_in[7];
    const float* Wf1  = (const float*)d_in[8];
    const float* bf1  = (const float*)d_in[9];
    const float* Wf2  = (const float*)d_in[10];
    const float* bf2  = (const float*)d_in[11];
    float* out = (float*)d_out;

    const int n = in_sizes[0] / C_IN;          // 50000
    const int E = in_sizes[1] / 2;             // 800000
    const int* src = ei;
    const int* dst = ei + E;
    const int nbk = (n + 255) >> BKT_SHIFT;    // 196 buckets

    // ---- workspace layout (float offsets) ----
    float* ws = (float*)d_ws;
    float* dinv   = ws;                          // [n]
    float* invdeg = ws + (size_t)n;              // [n]
    float* part   = ws + (size_t)2 * n;          // [2n]
    float* buf1   = ws + (size_t)18 * n;         // [64n]
    float* buf2   = ws + (size_t)82 * n;         // [64n]
    float* buf3   = ws + (size_t)146 * n;        // [32n]
    int*   iw     = (int*)(ws + (size_t)178 * n);
    int*   row    = iw;                          // [n+1]
    int*   csr    = iw + (size_t)n + 1;          // [E]
    int*   bcnt   = iw + (size_t)n + 1 + E;      // [NBK_MAX]
    int*   bbase  = bcnt + NBK_MAX;              // [NBK_MAX+1]
    int*   bcur   = bbase + NBK_MAX + 1;         // [NBK_MAX]
    int2*  pairs  = (int2*)buf2;                 // [E], dead after build
    (void)ws_size; (void)n_in; (void)out_size;

    const int nb_n = (n + NTH - 1) / NTH;        // 196

    hipMemsetAsync(bcnt, 0, NBK_MAX * sizeof(int), stream);

    // buffer plan (bf16 buffers sized in float-equivalents):
    unsigned short* xs1 = (unsigned short*)buf1;              // 16ch bf16 = 8n fl
    float* ga1 = buf2;                                        // 16n fl (pairs dead)
    float* h1  = buf3;                                        // 32n fl
    unsigned short* xs2 = (unsigned short*)buf1;              // 32ch bf16 = 16n fl (xs1 dead)
    float* ga2 = buf2;                                        // 32n fl
    unsigned short* t3  = (unsigned short*)buf1;              // 32ch bf16 = 16n fl (xs2 dead)
    unsigned short* ts3 = (unsigned short*)(buf1 + (size_t)16 * n);  // 32ch bf16 = 16n fl
    unsigned short* h3  = (unsigned short*)buf3;              // 16n fl (h1 dead)

    // ---- bucketed CSR build ----
    bkt_hist_kernel<<<128, NTH, 0, stream>>>(dst, E, nbk, bcnt);
    bkt_scan_kernel<<<1, NTH, 0, stream>>>(bcnt, nbk, bbase, bcur, row, n);
    bkt_scatter_kernel<<<128, NTH, 0, stream>>>(src, dst, E, nbk, bcur, pairs);
    build_kernel<<<nbk, NTH, 0, stream>>>(pairs, bbase, n, row, csr, dinv, invdeg, x, xs1);

    // layer 1: aggregate x (16ch bf16) then transform 16->32 (h1 fp32, xs2 bf16*dinv)
    gather_bf_kernel<16, false, false><<<(n + 127) / 128, NTH, 0, stream>>>(row, csr, xs1, x, dinv, invdeg, nullptr, ga1, n);
    transform1_kernel<<<nb_n, NTH, 0, stream>>>(ga1, W1, b1, dinv, h1, xs2, n);

    // layer 2: aggregate h1 via xs2 (32ch bf16), spill-free fused transform 32->64->32
    gather_bf_kernel<32, false, false><<<(n + 63) / 64, NTH, 0, stream>>>(row, csr, xs2, h1, dinv, invdeg, nullptr, ga2, n);
    transform23_kernel<<<nb_n, NTH, 0, stream>>>(ga2, W2, b2, W3, dinv, t3, ts3, n);

    // layer 3 aggregation (post-transform), self=t3 bf16, fuse b3+relu, h3 written bf16
    gather_bf_kernel<32, true, true><<<(n + 63) / 64, NTH, 0, stream>>>(row, csr, ts3, t3, dinv, invdeg, b3, h3, n);

    // MLP head: MFMA GEMM (h3 bf16 direct A-fragments) -> 2 partials, then sigmoid
    dim3 mgrid((n + 511) / 512, 2);
    mlp_mfma_kernel<<<mgrid, NTH, 0, stream>>>(h3, Wf1, bf1, Wf2, part, n);
    sigmoid_kernel<<<nb_n, NTH, 0, stream>>>(part, bf2, out, n);
}